// Round 5
// baseline (344.449 us; speedup 1.0000x reference)
//
#include <hip/hip_runtime.h>
#include <hip/hip_bf16.h>
#include <math.h>

#define B_ 4096
#define F_ 64
#define A_ 8
#define U_ 32

typedef float f32x4 __attribute__((ext_vector_type(4)));
typedef short bf16x8 __attribute__((ext_vector_type(8)));

// ws layout (fused path, 8.06 MB):
//   FRAG [0, 4 MB): per (a*64+j) 8192 B: [0,4096) K B-frags (fragid=kc*2+ut),
//                   [4096,8192) W B-frags (fragid=ft); 64 lanes x 16 B each.
//   KD   [4 MB, +64 KB): fp32 [(a*64+j)*32 + u] = rb(K[j,a][j][u])
//   PART [4 MB+64 KB, +4 MB): bf16 h=0 partials: [(a*4096 + row)*64 + f]
//   BAR  [+128 B): grid-barrier counter (memset to 0 每 launch)
#define KD_OFF   (4ull << 20)
#define PART_OFF ((4ull << 20) + (64ull << 10))
#define BAR_OFF  (PART_OFF + (4ull << 20))
#define WS_NEED  (BAR_OFF + 128ull)

static __device__ __forceinline__ unsigned int pk_bf16(float lo, float hi) {
    union { __hip_bfloat162 h2; unsigned int u; } cv;
    cv.h2 = __float22bfloat162_rn(make_float2(lo, hi));
    return cv.u;
}
static __device__ __forceinline__ unsigned short rne16(float f) {
    unsigned int u = __float_as_uint(f);
    u += 0x7FFFu + ((u >> 16) & 1u);
    return (unsigned short)(u >> 16);
}
static __device__ __forceinline__ float rb(float f) {   // fp32 -> bf16 -> fp32
    unsigned int u = __float_as_uint(f);
    u += 0x7FFFu + ((u >> 16) & 1u);
    return __uint_as_float(u & 0xFFFF0000u);
}
static __device__ __forceinline__ float b2f(unsigned short h) {
    return __uint_as_float(((unsigned int)h) << 16);
}

// Manual grid barrier (all 512 blocks co-resident by construction).
// Release: every thread agent-fences, then thread0 atomically arrives.
// Acquire: thread0 spins, then every thread agent-fences.
static __device__ __forceinline__ void grid_barrier(unsigned int* bar, unsigned int target) {
    __threadfence();
    __syncthreads();
    if (threadIdx.x == 0) {
        __hip_atomic_fetch_add(bar, 1u, __ATOMIC_ACQ_REL, __HIP_MEMORY_SCOPE_AGENT);
        while (__hip_atomic_load(bar, __ATOMIC_RELAXED, __HIP_MEMORY_SCOPE_AGENT) < target)
            __builtin_amdgcn_s_sleep(1);
    }
    __syncthreads();
    __threadfence();
}

// ================= fused: 512 blocks, 3 phases, 2 manual grid barriers =================
__global__ __launch_bounds__(256, 2)
void ife_fused(const float* __restrict__ x,     // [B, F]
               const float* __restrict__ kern,  // [j=F, A, F, U]
               unsigned char* __restrict__ ws,
               float* __restrict__ out)         // [A, B, F]
{
    const int b = blockIdx.x, t = threadIdx.x;
    const int wv = t >> 6, lane = t & 63, q = lane >> 4, c = lane & 15;
    unsigned int* bar = (unsigned int*)(ws + BAR_OFF);

    __shared__ union {
        float st[64][36];                       // phase 1 staging
        struct {
            float Xf[128][33];                  // rb-rounded x, this j-half's columns
            float Kd[32][32];                   // rb-rounded K[j][j][u], this j-half
            unsigned int Pbuf[4][2][16][20];    // wave-private E round-trip
        } p2;
    } sh;

    // ---------------- PHASE 1: prep frags for (ap, jp) = (b>>6, b&63) ----------------
    {
        const int ap = b >> 6, jp = b & 63;
        const float* src = kern + ((size_t)jp * A_ + ap) * (F_ * U_);
        {
            const int f = t >> 2, u0 = (t & 3) * 8;
            *(float4*)&sh.st[f][u0]     = *(const float4*)&src[f * U_ + u0];
            *(float4*)&sh.st[f][u0 + 4] = *(const float4*)&src[f * U_ + u0 + 4];
        }
        __syncthreads();
        unsigned char* dst = ws + (size_t)b * 8192;
        const int fragid = t >> 6;
        {   // K B-frag (fragid = kc*2 + ut): bf16 K[f=kc*32+q*8+jj][u=ut*16+c]
            const int kc = fragid >> 1, ut = fragid & 1;
            const int f0 = kc * 32 + q * 8, u = ut * 16 + c;
            unsigned int w[4];
            #pragma unroll
            for (int i = 0; i < 4; ++i)
                w[i] = pk_bf16(sh.st[f0 + 2 * i][u], sh.st[f0 + 2 * i + 1][u]);
            *(uint4*)(dst + fragid * 1024 + lane * 16) = make_uint4(w[0], w[1], w[2], w[3]);
        }
        {   // W B-frag (fragid = ft): bf16 exp(2*K[f=ft*16+c][u=q*8+jj])
            const int ff = fragid * 16 + c, u0 = q * 8;
            const float4 wa = *(const float4*)&sh.st[ff][u0];
            const float4 wb = *(const float4*)&sh.st[ff][u0 + 4];
            unsigned int w[4];
            w[0] = pk_bf16(__expf(2.f * wa.x), __expf(2.f * wa.y));
            w[1] = pk_bf16(__expf(2.f * wa.z), __expf(2.f * wa.w));
            w[2] = pk_bf16(__expf(2.f * wb.x), __expf(2.f * wb.y));
            w[3] = pk_bf16(__expf(2.f * wb.z), __expf(2.f * wb.w));
            *(uint4*)(dst + 4096 + fragid * 1024 + lane * 16) = make_uint4(w[0], w[1], w[2], w[3]);
        }
        if (t < U_)
            ((float*)(ws + KD_OFF))[(size_t)b * U_ + t] = rb(sh.st[b & 63][t]);
    }
    grid_barrier(bar, 512u);

    // ---------------- PHASE 2: partial scores; block = (a, bt, h) ----------------
    const int a = b >> 6, bt = (b >> 1) & 31, h = b & 1;
    const int R0 = bt * 128;                    // rows [R0, R0+128)

    bf16x8 Xh[2][2];
    #pragma unroll
    for (int rg = 0; rg < 2; ++rg) {
        const float* xr = x + (size_t)(R0 + wv * 32 + rg * 16 + c) * F_;
        #pragma unroll
        for (int kc = 0; kc < 2; ++kc) {
            const float4 va = *(const float4*)&xr[kc * 32 + q * 8];
            const float4 vb = *(const float4*)&xr[kc * 32 + q * 8 + 4];
            union { unsigned int u[4]; bf16x8 v; } H;
            H.u[0] = pk_bf16(va.x, va.y);
            H.u[1] = pk_bf16(va.z, va.w);
            H.u[2] = pk_bf16(vb.x, vb.y);
            H.u[3] = pk_bf16(vb.z, vb.w);
            Xh[rg][kc] = H.v;
        }
    }
    {   // Xf: rb-rounded x, this half's 32 columns
        const int row = t >> 1, cs = (t & 1) * 16;
        const float* xsrc = x + (size_t)(R0 + row) * F_ + h * 32 + cs;
        #pragma unroll
        for (int i = 0; i < 16; i += 4) {
            const float4 v = *(const float4*)&xsrc[i];
            sh.p2.Xf[row][cs + i]     = rb(v.x);
            sh.p2.Xf[row][cs + i + 1] = rb(v.y);
            sh.p2.Xf[row][cs + i + 2] = rb(v.z);
            sh.p2.Xf[row][cs + i + 3] = rb(v.w);
        }
    }
    {   // Kd: this a, this j-half
        const int jl = t >> 3, u0 = (t & 7) * 4;
        const float* kd = (const float*)(ws + KD_OFF) + ((size_t)(a * 64 + h * 32 + jl)) * U_ + u0;
        *(float4*)&sh.p2.Kd[jl][u0] = *(const float4*)kd;
    }
    __syncthreads();

    const unsigned int psel = (q < 2) ? 0x05040100u : 0x07060302u;
    const unsigned char* fbase = ws + (size_t)(a * 64 + h * 32) * 8192 + (size_t)lane * 16;

    union { unsigned int u[4]; bf16x8 v; } oc;
    oc.u[0] = 0x3F803F80u; oc.u[1] = 0x3F803F80u; oc.u[2] = 0x3F803F80u; oc.u[3] = 0x3F803F80u;
    const bf16x8 ONES = oc.v;
    const f32x4 vzero = (f32x4){0.f, 0.f, 0.f, 0.f};

    f32x4 S[2][4];
    #pragma unroll
    for (int rg = 0; rg < 2; ++rg)
        #pragma unroll
        for (int ft = 0; ft < 4; ++ft) S[rg][ft] = vzero;

    bf16x8 KA[4], WA[4], KB[4], WB[4];
    auto LOADF = [&](bf16x8* K, bf16x8* W, int jl) {
        const unsigned char* p = fbase + (size_t)jl * 8192;
        #pragma unroll
        for (int i = 0; i < 4; ++i) {
            K[i] = *(const bf16x8*)(p + i * 1024);
            W[i] = *(const bf16x8*)(p + 4096 + i * 1024);
        }
    };

    auto BODY = [&](const bf16x8* K, const bf16x8* W, int jl) {
        f32x4 ZA[2], ZB[2];
        #pragma unroll
        for (int rg = 0; rg < 2; ++rg) {
            f32x4 za = vzero, zb = vzero;
            za = __builtin_amdgcn_mfma_f32_16x16x32_bf16(Xh[rg][0], K[0], za, 0, 0, 0);
            za = __builtin_amdgcn_mfma_f32_16x16x32_bf16(Xh[rg][1], K[2], za, 0, 0, 0);
            zb = __builtin_amdgcn_mfma_f32_16x16x32_bf16(Xh[rg][0], K[1], zb, 0, 0, 0);
            zb = __builtin_amdgcn_mfma_f32_16x16x32_bf16(Xh[rg][1], K[3], zb, 0, 0, 0);
            ZA[rg] = za; ZB[rg] = zb;
        }
        const float kd0 = sh.p2.Kd[jl][c], kd1 = sh.p2.Kd[jl][16 + c];
        #pragma unroll
        for (int rg = 0; rg < 2; ++rg)
            #pragma unroll
            for (int r = 0; r < 4; ++r) {
                const float xj = sh.p2.Xf[wv * 32 + rg * 16 + q * 4 + r][jl];
                const float e0 = __expf(ZA[rg][r] - xj * kd0);
                const float e1 = __expf(ZB[rg][r] - xj * kd1);
                sh.p2.Pbuf[wv][rg][q * 4 + r][c] = pk_bf16(e0, e1);
            }
        asm volatile("s_waitcnt lgkmcnt(0)" ::: "memory");
        union { unsigned int u[4]; bf16x8 v; } E[2];
        #pragma unroll
        for (int rg = 0; rg < 2; ++rg) {
            const uint4 pa = *(const uint4*)&sh.p2.Pbuf[wv][rg][c][(q & 1) * 8];
            const uint4 pb = *(const uint4*)&sh.p2.Pbuf[wv][rg][c][(q & 1) * 8 + 4];
            E[rg].u[0] = __builtin_amdgcn_perm(pa.y, pa.x, psel);
            E[rg].u[1] = __builtin_amdgcn_perm(pa.w, pa.z, psel);
            E[rg].u[2] = __builtin_amdgcn_perm(pb.y, pb.x, psel);
            E[rg].u[3] = __builtin_amdgcn_perm(pb.w, pb.z, psel);
        }
        #pragma unroll
        for (int rg = 0; rg < 2; ++rg) {
            const f32x4 sv = __builtin_amdgcn_mfma_f32_16x16x32_bf16(E[rg].v, ONES, vzero, 0, 0, 0);
            f32x4 D[4];
            #pragma unroll
            for (int ft = 0; ft < 4; ++ft)
                D[ft] = __builtin_amdgcn_mfma_f32_16x16x32_bf16(E[rg].v, W[ft], vzero, 0, 0, 0);
            #pragma unroll
            for (int r = 0; r < 4; ++r) {
                const float inv = __builtin_amdgcn_rcpf(sv[r]);
                #pragma unroll
                for (int ft = 0; ft < 4; ++ft) S[rg][ft][r] += D[ft][r] * inv;
            }
        }
    };

    LOADF(KA, WA, 0);
    for (int jl = 0; jl < 32; jl += 2) {
        LOADF(KB, WB, jl + 1);
        BODY(KA, WA, jl);
        LOADF(KA, WA, (jl + 2 < 32) ? (jl + 2) : 31);
        BODY(KB, WB, jl + 1);
    }

    // partial store: h=0 -> bf16 in ws, h=1 -> fp32 into out (overwritten in phase 3)
    {
        const float sc = 1.f / 64.f;
        if (h == 0) {
            unsigned short* part = (unsigned short*)(ws + PART_OFF);
            #pragma unroll
            for (int rg = 0; rg < 2; ++rg)
                #pragma unroll
                for (int r = 0; r < 4; ++r) {
                    const int row = R0 + wv * 32 + rg * 16 + q * 4 + r;
                    unsigned short* p = part + ((size_t)a * 4096 + row) * 64 + c;
                    p[0]  = rne16(S[rg][0][r] * sc);
                    p[16] = rne16(S[rg][1][r] * sc);
                    p[32] = rne16(S[rg][2][r] * sc);
                    p[48] = rne16(S[rg][3][r] * sc);
                }
        } else {
            #pragma unroll
            for (int rg = 0; rg < 2; ++rg)
                #pragma unroll
                for (int r = 0; r < 4; ++r) {
                    const int row = R0 + wv * 32 + rg * 16 + q * 4 + r;
                    float* p = out + ((size_t)a * B_ + row) * F_ + c;
                    p[0]  = S[rg][0][r] * sc;
                    p[16] = S[rg][1][r] * sc;
                    p[32] = S[rg][2][r] * sc;
                    p[48] = S[rg][3][r] * sc;
                }
        }
    }
    grid_barrier(bar, 1024u);

    // ---------------- PHASE 3: combine halves + softmax over f ----------------
    {
        const unsigned short* part = (const unsigned short*)(ws + PART_OFF);
        const int Row0 = bt * 128 + h * 64;
        #pragma unroll
        for (int r = 0; r < 4; ++r) {
            const int row = Row0 + wv * 16 + q * 4 + r;
            const unsigned short* P0 = part + ((size_t)a * 4096 + row) * 64 + c;
            float* o = out + ((size_t)a * B_ + row) * F_ + c;
            const float v0 = b2f(P0[0])  + o[0];
            const float v1 = b2f(P0[16]) + o[16];
            const float v2 = b2f(P0[32]) + o[32];
            const float v3 = b2f(P0[48]) + o[48];
            const float e0 = __expf(v0), e1 = __expf(v1);
            const float e2 = __expf(v2), e3 = __expf(v3);
            float s = e0 + e1 + e2 + e3;
            s += __shfl_xor(s, 1);
            s += __shfl_xor(s, 2);
            s += __shfl_xor(s, 4);
            s += __shfl_xor(s, 8);
            const float inv = 1.f / s;
            o[0]  = e0 * inv;
            o[16] = e1 * inv;
            o[32] = e2 * inv;
            o[48] = e3 * inv;
        }
    }
}

// ================= fallback (round-3 proven path, used only if ws too small) =================
__global__ __launch_bounds__(256) void ife_prep(const float* __restrict__ kern,
                                                unsigned char* __restrict__ ws)
{
    const int bid = blockIdx.x;
    const int a = bid >> 6, j = bid & 63;
    const int t = threadIdx.x;
    __shared__ float st[64][36];
    const float* src = kern + ((size_t)j * A_ + a) * (F_ * U_);
    {
        const int f = t >> 2, u0 = (t & 3) * 8;
        *(float4*)&st[f][u0]     = *(const float4*)&src[f * U_ + u0];
        *(float4*)&st[f][u0 + 4] = *(const float4*)&src[f * U_ + u0 + 4];
    }
    __syncthreads();
    unsigned char* dst = ws + (size_t)bid * 8192;
    const int fragid = t >> 6, lane = t & 63, q = lane >> 4, c = lane & 15;
    {
        const int kc = fragid >> 1, ut = fragid & 1;
        const int f0 = kc * 32 + q * 8, u = ut * 16 + c;
        unsigned int w[4];
        #pragma unroll
        for (int i = 0; i < 4; ++i)
            w[i] = pk_bf16(st[f0 + 2 * i][u], st[f0 + 2 * i + 1][u]);
        *(uint4*)(dst + fragid * 1024 + lane * 16) = make_uint4(w[0], w[1], w[2], w[3]);
    }
    {
        const int ff = fragid * 16 + c, u0 = q * 8;
        const float4 wa = *(const float4*)&st[ff][u0];
        const float4 wb = *(const float4*)&st[ff][u0 + 4];
        unsigned int w[4];
        w[0] = pk_bf16(__expf(2.f * wa.x), __expf(2.f * wa.y));
        w[1] = pk_bf16(__expf(2.f * wa.z), __expf(2.f * wa.w));
        w[2] = pk_bf16(__expf(2.f * wb.x), __expf(2.f * wb.y));
        w[3] = pk_bf16(__expf(2.f * wb.z), __expf(2.f * wb.w));
        *(uint4*)(dst + 4096 + fragid * 1024 + lane * 16) = make_uint4(w[0], w[1], w[2], w[3]);
    }
    if (t < U_)
        ((float*)(ws + KD_OFF))[(size_t)bid * U_ + t] = rb(st[j][t]);
}

__global__ __launch_bounds__(256, 2) void ife_main(const float* __restrict__ x,
                                                   const unsigned char* __restrict__ ws,
                                                   float* __restrict__ out)
{
    const int a = blockIdx.y, bt = blockIdx.x, t = threadIdx.x;
    const int wv = t >> 6, lane = t & 63, q = lane >> 4, c = lane & 15;
    __shared__ float Xf[64][66];
    __shared__ float Kd[64][32];
    __shared__ __align__(16) unsigned int Pbuf[4][16][20];

    bf16x8 Xh[2];
    {
        const float* xr = x + (size_t)(bt * 64 + wv * 16 + c) * F_;
        #pragma unroll
        for (int kc = 0; kc < 2; ++kc) {
            const float4 va = *(const float4*)&xr[kc * 32 + q * 8];
            const float4 vb = *(const float4*)&xr[kc * 32 + q * 8 + 4];
            union { unsigned int u[4]; bf16x8 v; } H;
            H.u[0] = pk_bf16(va.x, va.y);
            H.u[1] = pk_bf16(va.z, va.w);
            H.u[2] = pk_bf16(vb.x, vb.y);
            H.u[3] = pk_bf16(vb.z, vb.w);
            Xh[kc] = H.v;
        }
    }
    {
        const int row = t >> 2, cb = (t & 3) * 16;
        const float* xsrc = x + (size_t)(bt * 64 + row) * F_ + cb;
        #pragma unroll
        for (int i = 0; i < 16; i += 4) {
            const float4 v = *(const float4*)&xsrc[i];
            Xf[row][cb + i]     = rb(v.x);
            Xf[row][cb + i + 1] = rb(v.y);
            Xf[row][cb + i + 2] = rb(v.z);
            Xf[row][cb + i + 3] = rb(v.w);
        }
    }
    {
        const float* kd = (const float*)(ws + KD_OFF) + (size_t)a * 64 * U_;
        const int jj = t >> 2, u0 = (t & 3) * 8;
        *(float4*)&Kd[jj][u0]     = *(const float4*)&kd[jj * U_ + u0];
        *(float4*)&Kd[jj][u0 + 4] = *(const float4*)&kd[jj * U_ + u0 + 4];
    }
    __syncthreads();

    const unsigned int psel = (q < 2) ? 0x05040100u : 0x07060302u;
    const unsigned char* fbase = ws + (size_t)a * 64 * 8192 + (size_t)lane * 16;
    union { unsigned int u[4]; bf16x8 v; } oc;
    oc.u[0] = 0x3F803F80u; oc.u[1] = 0x3F803F80u; oc.u[2] = 0x3F803F80u; oc.u[3] = 0x3F803F80u;
    const bf16x8 ONES = oc.v;
    const f32x4 vzero = (f32x4){0.f, 0.f, 0.f, 0.f};
    f32x4 S0 = vzero, S1 = vzero, S2 = vzero, S3 = vzero;
    bf16x8 KA[4], WA[4], KB[4], WB[4];

    auto LOADF = [&](bf16x8* K, bf16x8* W, int jj) {
        const unsigned char* p = fbase + (size_t)jj * 8192;
        #pragma unroll
        for (int i = 0; i < 4; ++i) {
            K[i] = *(const bf16x8*)(p + i * 1024);
            W[i] = *(const bf16x8*)(p + 4096 + i * 1024);
        }
    };
    auto BODY = [&](const bf16x8* K, const bf16x8* W, int j) {
        f32x4 ZA = vzero, ZB = vzero;
        ZA = __builtin_amdgcn_mfma_f32_16x16x32_bf16(Xh[0], K[0], ZA, 0, 0, 0);
        ZA = __builtin_amdgcn_mfma_f32_16x16x32_bf16(Xh[1], K[2], ZA, 0, 0, 0);
        ZB = __builtin_amdgcn_mfma_f32_16x16x32_bf16(Xh[0], K[1], ZB, 0, 0, 0);
        ZB = __builtin_amdgcn_mfma_f32_16x16x32_bf16(Xh[1], K[3], ZB, 0, 0, 0);
        const float kd0 = Kd[j][c], kd1 = Kd[j][16 + c];
        #pragma unroll
        for (int r = 0; r < 4; ++r) {
            const float xj = Xf[wv * 16 + q * 4 + r][j];
            const float e0 = __expf(ZA[r] - xj * kd0);
            const float e1 = __expf(ZB[r] - xj * kd1);
            Pbuf[wv][q * 4 + r][c] = pk_bf16(e0, e1);
        }
        asm volatile("s_waitcnt lgkmcnt(0)" ::: "memory");
        union { unsigned int u[4]; bf16x8 v; } E;
        {
            const uint4 pa = *(const uint4*)&Pbuf[wv][c][(q & 1) * 8];
            const uint4 pb = *(const uint4*)&Pbuf[wv][c][(q & 1) * 8 + 4];
            E.u[0] = __builtin_amdgcn_perm(pa.y, pa.x, psel);
            E.u[1] = __builtin_amdgcn_perm(pa.w, pa.z, psel);
            E.u[2] = __builtin_amdgcn_perm(pb.y, pb.x, psel);
            E.u[3] = __builtin_amdgcn_perm(pb.w, pb.z, psel);
        }
        const f32x4 sv = __builtin_amdgcn_mfma_f32_16x16x32_bf16(E.v, ONES, vzero, 0, 0, 0);
        f32x4 D0 = __builtin_amdgcn_mfma_f32_16x16x32_bf16(E.v, W[0], vzero, 0, 0, 0);
        f32x4 D1 = __builtin_amdgcn_mfma_f32_16x16x32_bf16(E.v, W[1], vzero, 0, 0, 0);
        f32x4 D2 = __builtin_amdgcn_mfma_f32_16x16x32_bf16(E.v, W[2], vzero, 0, 0, 0);
        f32x4 D3 = __builtin_amdgcn_mfma_f32_16x16x32_bf16(E.v, W[3], vzero, 0, 0, 0);
        #pragma unroll
        for (int r = 0; r < 4; ++r) {
            const float inv = __builtin_amdgcn_rcpf(sv[r]);
            S0[r] += D0[r] * inv;
            S1[r] += D1[r] * inv;
            S2[r] += D2[r] * inv;
            S3[r] += D3[r] * inv;
        }
    };

    LOADF(KA, WA, 0);
    for (int j = 0; j < 64; j += 2) {
        LOADF(KB, WB, j + 1);
        BODY(KA, WA, j);
        LOADF(KA, WA, (j + 2 < 64) ? (j + 2) : 63);
        BODY(KB, WB, j + 1);
    }
    const float sc = 1.f / 64.f;
    #pragma unroll
    for (int r = 0; r < 4; ++r) {
        const float e0 = __expf(S0[r] * sc);
        const float e1 = __expf(S1[r] * sc);
        const float e2 = __expf(S2[r] * sc);
        const float e3 = __expf(S3[r] * sc);
        float s = e0 + e1 + e2 + e3;
        s += __shfl_xor(s, 1);
        s += __shfl_xor(s, 2);
        s += __shfl_xor(s, 4);
        s += __shfl_xor(s, 8);
        const float inv = 1.f / s;
        const int bb = bt * 64 + wv * 16 + q * 4 + r;
        float* o = out + ((size_t)a * B_ + bb) * F_ + c;
        o[0]  = e0 * inv;
        o[16] = e1 * inv;
        o[32] = e2 * inv;
        o[48] = e3 * inv;
    }
}

extern "C" void kernel_launch(void* const* d_in, const int* in_sizes, int n_in,
                              void* d_out, int out_size, void* d_ws, size_t ws_size,
                              hipStream_t stream) {
    (void)in_sizes; (void)n_in; (void)out_size;
    const float* x    = (const float*)d_in[0];
    const float* kern = (const float*)d_in[1];
    float* out        = (float*)d_out;
    unsigned char* ws = (unsigned char*)d_ws;

    if (ws_size >= WS_NEED) {
        hipMemsetAsync(ws + BAR_OFF, 0, 128, stream);
        hipLaunchKernelGGL(ife_fused, dim3(512), dim3(256), 0, stream, x, kern, ws, out);
    } else {
        hipLaunchKernelGGL(ife_prep, dim3(F_ * A_), dim3(256), 0, stream, kern, ws);
        hipLaunchKernelGGL(ife_main, dim3(B_ / 64, A_), dim3(256), 0, stream, x, ws, out);
    }
}

// Round 6
// 150.574 us; speedup vs baseline: 2.2876x; 2.2876x over previous
//
#include <hip/hip_runtime.h>
#include <hip/hip_bf16.h>
#include <math.h>

#define B_ 4096
#define F_ 64
#define A_ 8
#define U_ 32

typedef float f32x4 __attribute__((ext_vector_type(4)));
typedef short bf16x8 __attribute__((ext_vector_type(8)));

// ws layout (fused path, ~8.07 MB):
//   FRAG [0, 4 MB): per (a*64+j) 8192 B: [0,4096) K B-frags (fragid=kc*2+ut),
//                   [4096,8192) W B-frags (fragid=ft); 64 lanes x 16 B each.
//   KD   [4 MB, +64 KB): fp32 [(a*64+j)*32 + u] = rb(K[j,a][j][u])
//   PART [4 MB+64 KB, +4 MB): bf16 h=0 partials: [(a*4096 + row)*64 + f]
//   SLOT0/SLOT1 [+2 KB each): tag-slot grid barriers (no zero-init needed)
#define KD_OFF    (4ull << 20)
#define PART_OFF  ((4ull << 20) + (64ull << 10))
#define SLOT0_OFF (PART_OFF + (4ull << 20))
#define SLOT1_OFF (SLOT0_OFF + 2048ull)
#define WS_NEED   (SLOT1_OFF + 2048ull)

#define TAG1 0x1CEB0000u
#define TAG2 0x2CEB0000u

static __device__ __forceinline__ unsigned int pk_bf16(float lo, float hi) {
    union { __hip_bfloat162 h2; unsigned int u; } cv;
    cv.h2 = __float22bfloat162_rn(make_float2(lo, hi));
    return cv.u;
}
static __device__ __forceinline__ unsigned short rne16(float f) {
    unsigned int u = __float_as_uint(f);
    u += 0x7FFFu + ((u >> 16) & 1u);
    return (unsigned short)(u >> 16);
}
static __device__ __forceinline__ float rb(float f) {   // fp32 -> bf16 -> fp32
    unsigned int u = __float_as_uint(f);
    u += 0x7FFFu + ((u >> 16) & 1u);
    return __uint_as_float(u & 0xFFFF0000u);
}
static __device__ __forceinline__ float b2f(unsigned short h) {
    return __uint_as_float(((unsigned int)h) << 16);
}

// Tag-slot grid barrier: 512 slots, block b publishes TAG|b; each of the 256
// threads polls 2 slots. Fences are thread-0-only (one wbL2 release + one
// invL1/L2 acquire per block), NOT per-thread — that was round 5's 240 us stall.
// No counter => no zero-init => no extra memset node in the graph.
static __device__ __forceinline__ void grid_barrier(unsigned int* slots, unsigned int tag) {
    __syncthreads();   // all waves' global stores are vmcnt-drained into L2 here
    if (threadIdx.x == 0) {
        __builtin_amdgcn_fence(__ATOMIC_RELEASE, "agent");   // writeback L2
        __hip_atomic_store(&slots[blockIdx.x], tag | blockIdx.x,
                           __ATOMIC_RELAXED, __HIP_MEMORY_SCOPE_AGENT);
    }
    const unsigned int i0 = threadIdx.x * 2, i1 = i0 + 1;
    const unsigned int e0 = tag | i0, e1 = tag | i1;
    while (__hip_atomic_load(&slots[i0], __ATOMIC_RELAXED, __HIP_MEMORY_SCOPE_AGENT) != e0)
        __builtin_amdgcn_s_sleep(4);
    while (__hip_atomic_load(&slots[i1], __ATOMIC_RELAXED, __HIP_MEMORY_SCOPE_AGENT) != e1)
        __builtin_amdgcn_s_sleep(4);
    __syncthreads();
    if (threadIdx.x == 0)
        __builtin_amdgcn_fence(__ATOMIC_ACQUIRE, "agent");   // invalidate L1/L2
    __syncthreads();
}

// ================= fused: 512 blocks, 3 phases, 2 tag-slot barriers =================
__global__ __launch_bounds__(256, 2)
void ife_fused(const float* __restrict__ x,     // [B, F]
               const float* __restrict__ kern,  // [j=F, A, F, U]
               unsigned char* __restrict__ ws,
               float* __restrict__ out)         // [A, B, F]
{
    const int b = blockIdx.x, t = threadIdx.x;
    const int wv = t >> 6, lane = t & 63, q = lane >> 4, c = lane & 15;

    __shared__ union {
        float st[64][36];                       // phase 1 staging
        struct {
            float Xf[128][33];                  // rb-rounded x, this j-half's columns
            float Kd[32][32];                   // rb-rounded K[j][j][u], this j-half
            unsigned int Pbuf[4][2][16][20];    // wave-private E round-trip
        } p2;
    } sh;

    // ---------------- PHASE 1: prep frags for (ap, jp) = (b>>6, b&63) ----------------
    {
        const int ap = b >> 6, jp = b & 63;
        const float* src = kern + ((size_t)jp * A_ + ap) * (F_ * U_);
        {
            const int f = t >> 2, u0 = (t & 3) * 8;
            *(float4*)&sh.st[f][u0]     = *(const float4*)&src[f * U_ + u0];
            *(float4*)&sh.st[f][u0 + 4] = *(const float4*)&src[f * U_ + u0 + 4];
        }
        __syncthreads();
        unsigned char* dst = ws + (size_t)b * 8192;
        const int fragid = t >> 6;
        {   // K B-frag (fragid = kc*2 + ut): bf16 K[f=kc*32+q*8+jj][u=ut*16+c]
            const int kc = fragid >> 1, ut = fragid & 1;
            const int f0 = kc * 32 + q * 8, u = ut * 16 + c;
            unsigned int w[4];
            #pragma unroll
            for (int i = 0; i < 4; ++i)
                w[i] = pk_bf16(sh.st[f0 + 2 * i][u], sh.st[f0 + 2 * i + 1][u]);
            *(uint4*)(dst + fragid * 1024 + lane * 16) = make_uint4(w[0], w[1], w[2], w[3]);
        }
        {   // W B-frag (fragid = ft): bf16 exp(2*K[f=ft*16+c][u=q*8+jj])
            const int ff = fragid * 16 + c, u0 = q * 8;
            const float4 wa = *(const float4*)&sh.st[ff][u0];
            const float4 wb = *(const float4*)&sh.st[ff][u0 + 4];
            unsigned int w[4];
            w[0] = pk_bf16(__expf(2.f * wa.x), __expf(2.f * wa.y));
            w[1] = pk_bf16(__expf(2.f * wa.z), __expf(2.f * wa.w));
            w[2] = pk_bf16(__expf(2.f * wb.x), __expf(2.f * wb.y));
            w[3] = pk_bf16(__expf(2.f * wb.z), __expf(2.f * wb.w));
            *(uint4*)(dst + 4096 + fragid * 1024 + lane * 16) = make_uint4(w[0], w[1], w[2], w[3]);
        }
        if (t < U_)
            ((float*)(ws + KD_OFF))[(size_t)b * U_ + t] = rb(sh.st[b & 63][t]);
    }
    grid_barrier((unsigned int*)(ws + SLOT0_OFF), TAG1);

    // ---------------- PHASE 2: partial scores; block = (a, bt, h) ----------------
    const int a = b >> 6, bt = (b >> 1) & 31, h = b & 1;
    const int R0 = bt * 128;                    // rows [R0, R0+128)

    bf16x8 Xh[2][2];
    #pragma unroll
    for (int rg = 0; rg < 2; ++rg) {
        const float* xr = x + (size_t)(R0 + wv * 32 + rg * 16 + c) * F_;
        #pragma unroll
        for (int kc = 0; kc < 2; ++kc) {
            const float4 va = *(const float4*)&xr[kc * 32 + q * 8];
            const float4 vb = *(const float4*)&xr[kc * 32 + q * 8 + 4];
            union { unsigned int u[4]; bf16x8 v; } H;
            H.u[0] = pk_bf16(va.x, va.y);
            H.u[1] = pk_bf16(va.z, va.w);
            H.u[2] = pk_bf16(vb.x, vb.y);
            H.u[3] = pk_bf16(vb.z, vb.w);
            Xh[rg][kc] = H.v;
        }
    }
    {   // Xf: rb-rounded x, this half's 32 columns
        const int row = t >> 1, cs = (t & 1) * 16;
        const float* xsrc = x + (size_t)(R0 + row) * F_ + h * 32 + cs;
        #pragma unroll
        for (int i = 0; i < 16; i += 4) {
            const float4 v = *(const float4*)&xsrc[i];
            sh.p2.Xf[row][cs + i]     = rb(v.x);
            sh.p2.Xf[row][cs + i + 1] = rb(v.y);
            sh.p2.Xf[row][cs + i + 2] = rb(v.z);
            sh.p2.Xf[row][cs + i + 3] = rb(v.w);
        }
    }
    {   // Kd: this a, this j-half
        const int jl = t >> 3, u0 = (t & 7) * 4;
        const float* kd = (const float*)(ws + KD_OFF) + ((size_t)(a * 64 + h * 32 + jl)) * U_ + u0;
        *(float4*)&sh.p2.Kd[jl][u0] = *(const float4*)kd;
    }
    __syncthreads();

    const unsigned int psel = (q < 2) ? 0x05040100u : 0x07060302u;
    const unsigned char* fbase = ws + (size_t)(a * 64 + h * 32) * 8192 + (size_t)lane * 16;

    union { unsigned int u[4]; bf16x8 v; } oc;
    oc.u[0] = 0x3F803F80u; oc.u[1] = 0x3F803F80u; oc.u[2] = 0x3F803F80u; oc.u[3] = 0x3F803F80u;
    const bf16x8 ONES = oc.v;
    const f32x4 vzero = (f32x4){0.f, 0.f, 0.f, 0.f};

    f32x4 S[2][4];
    #pragma unroll
    for (int rg = 0; rg < 2; ++rg)
        #pragma unroll
        for (int ft = 0; ft < 4; ++ft) S[rg][ft] = vzero;

    bf16x8 KA[4], WA[4], KB[4], WB[4];
    auto LOADF = [&](bf16x8* K, bf16x8* W, int jl) {
        const unsigned char* p = fbase + (size_t)jl * 8192;
        #pragma unroll
        for (int i = 0; i < 4; ++i) {
            K[i] = *(const bf16x8*)(p + i * 1024);
            W[i] = *(const bf16x8*)(p + 4096 + i * 1024);
        }
    };

    auto BODY = [&](const bf16x8* K, const bf16x8* W, int jl) {
        f32x4 ZA[2], ZB[2];
        #pragma unroll
        for (int rg = 0; rg < 2; ++rg) {
            f32x4 za = vzero, zb = vzero;
            za = __builtin_amdgcn_mfma_f32_16x16x32_bf16(Xh[rg][0], K[0], za, 0, 0, 0);
            za = __builtin_amdgcn_mfma_f32_16x16x32_bf16(Xh[rg][1], K[2], za, 0, 0, 0);
            zb = __builtin_amdgcn_mfma_f32_16x16x32_bf16(Xh[rg][0], K[1], zb, 0, 0, 0);
            zb = __builtin_amdgcn_mfma_f32_16x16x32_bf16(Xh[rg][1], K[3], zb, 0, 0, 0);
            ZA[rg] = za; ZB[rg] = zb;
        }
        const float kd0 = sh.p2.Kd[jl][c], kd1 = sh.p2.Kd[jl][16 + c];
        #pragma unroll
        for (int rg = 0; rg < 2; ++rg)
            #pragma unroll
            for (int r = 0; r < 4; ++r) {
                const float xj = sh.p2.Xf[wv * 32 + rg * 16 + q * 4 + r][jl];
                const float e0 = __expf(ZA[rg][r] - xj * kd0);
                const float e1 = __expf(ZB[rg][r] - xj * kd1);
                sh.p2.Pbuf[wv][rg][q * 4 + r][c] = pk_bf16(e0, e1);
            }
        asm volatile("s_waitcnt lgkmcnt(0)" ::: "memory");
        union { unsigned int u[4]; bf16x8 v; } E[2];
        #pragma unroll
        for (int rg = 0; rg < 2; ++rg) {
            const uint4 pa = *(const uint4*)&sh.p2.Pbuf[wv][rg][c][(q & 1) * 8];
            const uint4 pb = *(const uint4*)&sh.p2.Pbuf[wv][rg][c][(q & 1) * 8 + 4];
            E[rg].u[0] = __builtin_amdgcn_perm(pa.y, pa.x, psel);
            E[rg].u[1] = __builtin_amdgcn_perm(pa.w, pa.z, psel);
            E[rg].u[2] = __builtin_amdgcn_perm(pb.y, pb.x, psel);
            E[rg].u[3] = __builtin_amdgcn_perm(pb.w, pb.z, psel);
        }
        #pragma unroll
        for (int rg = 0; rg < 2; ++rg) {
            const f32x4 sv = __builtin_amdgcn_mfma_f32_16x16x32_bf16(E[rg].v, ONES, vzero, 0, 0, 0);
            f32x4 D[4];
            #pragma unroll
            for (int ft = 0; ft < 4; ++ft)
                D[ft] = __builtin_amdgcn_mfma_f32_16x16x32_bf16(E[rg].v, W[ft], vzero, 0, 0, 0);
            #pragma unroll
            for (int r = 0; r < 4; ++r) {
                const float inv = __builtin_amdgcn_rcpf(sv[r]);
                #pragma unroll
                for (int ft = 0; ft < 4; ++ft) S[rg][ft][r] += D[ft][r] * inv;
            }
        }
    };

    LOADF(KA, WA, 0);
    for (int jl = 0; jl < 32; jl += 2) {
        LOADF(KB, WB, jl + 1);
        BODY(KA, WA, jl);
        LOADF(KA, WA, (jl + 2 < 32) ? (jl + 2) : 31);
        BODY(KB, WB, jl + 1);
    }

    // partial store: h=0 -> bf16 in ws, h=1 -> fp32 into out (overwritten in phase 3)
    {
        const float sc = 1.f / 64.f;
        if (h == 0) {
            unsigned short* part = (unsigned short*)(ws + PART_OFF);
            #pragma unroll
            for (int rg = 0; rg < 2; ++rg)
                #pragma unroll
                for (int r = 0; r < 4; ++r) {
                    const int row = R0 + wv * 32 + rg * 16 + q * 4 + r;
                    unsigned short* p = part + ((size_t)a * 4096 + row) * 64 + c;
                    p[0]  = rne16(S[rg][0][r] * sc);
                    p[16] = rne16(S[rg][1][r] * sc);
                    p[32] = rne16(S[rg][2][r] * sc);
                    p[48] = rne16(S[rg][3][r] * sc);
                }
        } else {
            #pragma unroll
            for (int rg = 0; rg < 2; ++rg)
                #pragma unroll
                for (int r = 0; r < 4; ++r) {
                    const int row = R0 + wv * 32 + rg * 16 + q * 4 + r;
                    float* p = out + ((size_t)a * B_ + row) * F_ + c;
                    p[0]  = S[rg][0][r] * sc;
                    p[16] = S[rg][1][r] * sc;
                    p[32] = S[rg][2][r] * sc;
                    p[48] = S[rg][3][r] * sc;
                }
        }
    }
    grid_barrier((unsigned int*)(ws + SLOT1_OFF), TAG2);

    // ---------------- PHASE 3: combine halves + softmax over f ----------------
    {
        const unsigned short* part = (const unsigned short*)(ws + PART_OFF);
        const int Row0 = bt * 128 + h * 64;
        #pragma unroll
        for (int r = 0; r < 4; ++r) {
            const int row = Row0 + wv * 16 + q * 4 + r;
            const unsigned short* P0 = part + ((size_t)a * 4096 + row) * 64 + c;
            float* o = out + ((size_t)a * B_ + row) * F_ + c;
            const float v0 = b2f(P0[0])  + o[0];
            const float v1 = b2f(P0[16]) + o[16];
            const float v2 = b2f(P0[32]) + o[32];
            const float v3 = b2f(P0[48]) + o[48];
            const float e0 = __expf(v0), e1 = __expf(v1);
            const float e2 = __expf(v2), e3 = __expf(v3);
            float s = e0 + e1 + e2 + e3;
            s += __shfl_xor(s, 1);
            s += __shfl_xor(s, 2);
            s += __shfl_xor(s, 4);
            s += __shfl_xor(s, 8);
            const float inv = 1.f / s;
            o[0]  = e0 * inv;
            o[16] = e1 * inv;
            o[32] = e2 * inv;
            o[48] = e3 * inv;
        }
    }
}

// ================= fallback (round-3 proven path, used only if ws too small) =================
__global__ __launch_bounds__(256) void ife_prep(const float* __restrict__ kern,
                                                unsigned char* __restrict__ ws)
{
    const int bid = blockIdx.x;
    const int a = bid >> 6, j = bid & 63;
    const int t = threadIdx.x;
    __shared__ float st[64][36];
    const float* src = kern + ((size_t)j * A_ + a) * (F_ * U_);
    {
        const int f = t >> 2, u0 = (t & 3) * 8;
        *(float4*)&st[f][u0]     = *(const float4*)&src[f * U_ + u0];
        *(float4*)&st[f][u0 + 4] = *(const float4*)&src[f * U_ + u0 + 4];
    }
    __syncthreads();
    unsigned char* dst = ws + (size_t)bid * 8192;
    const int fragid = t >> 6, lane = t & 63, q = lane >> 4, c = lane & 15;
    {
        const int kc = fragid >> 1, ut = fragid & 1;
        const int f0 = kc * 32 + q * 8, u = ut * 16 + c;
        unsigned int w[4];
        #pragma unroll
        for (int i = 0; i < 4; ++i)
            w[i] = pk_bf16(st[f0 + 2 * i][u], st[f0 + 2 * i + 1][u]);
        *(uint4*)(dst + fragid * 1024 + lane * 16) = make_uint4(w[0], w[1], w[2], w[3]);
    }
    {
        const int ff = fragid * 16 + c, u0 = q * 8;
        const float4 wa = *(const float4*)&st[ff][u0];
        const float4 wb = *(const float4*)&st[ff][u0 + 4];
        unsigned int w[4];
        w[0] = pk_bf16(__expf(2.f * wa.x), __expf(2.f * wa.y));
        w[1] = pk_bf16(__expf(2.f * wa.z), __expf(2.f * wa.w));
        w[2] = pk_bf16(__expf(2.f * wb.x), __expf(2.f * wb.y));
        w[3] = pk_bf16(__expf(2.f * wb.z), __expf(2.f * wb.w));
        *(uint4*)(dst + 4096 + fragid * 1024 + lane * 16) = make_uint4(w[0], w[1], w[2], w[3]);
    }
    if (t < U_)
        ((float*)(ws + KD_OFF))[(size_t)bid * U_ + t] = rb(st[j][t]);
}

__global__ __launch_bounds__(256, 2) void ife_main(const float* __restrict__ x,
                                                   const unsigned char* __restrict__ ws,
                                                   float* __restrict__ out)
{
    const int a = blockIdx.y, bt = blockIdx.x, t = threadIdx.x;
    const int wv = t >> 6, lane = t & 63, q = lane >> 4, c = lane & 15;
    __shared__ float Xf[64][66];
    __shared__ float Kd[64][32];
    __shared__ __align__(16) unsigned int Pbuf[4][16][20];

    bf16x8 Xh[2];
    {
        const float* xr = x + (size_t)(bt * 64 + wv * 16 + c) * F_;
        #pragma unroll
        for (int kc = 0; kc < 2; ++kc) {
            const float4 va = *(const float4*)&xr[kc * 32 + q * 8];
            const float4 vb = *(const float4*)&xr[kc * 32 + q * 8 + 4];
            union { unsigned int u[4]; bf16x8 v; } H;
            H.u[0] = pk_bf16(va.x, va.y);
            H.u[1] = pk_bf16(va.z, va.w);
            H.u[2] = pk_bf16(vb.x, vb.y);
            H.u[3] = pk_bf16(vb.z, vb.w);
            Xh[kc] = H.v;
        }
    }
    {
        const int row = t >> 2, cb = (t & 3) * 16;
        const float* xsrc = x + (size_t)(bt * 64 + row) * F_ + cb;
        #pragma unroll
        for (int i = 0; i < 16; i += 4) {
            const float4 v = *(const float4*)&xsrc[i];
            Xf[row][cb + i]     = rb(v.x);
            Xf[row][cb + i + 1] = rb(v.y);
            Xf[row][cb + i + 2] = rb(v.z);
            Xf[row][cb + i + 3] = rb(v.w);
        }
    }
    {
        const float* kd = (const float*)(ws + KD_OFF) + (size_t)a * 64 * U_;
        const int jj = t >> 2, u0 = (t & 3) * 8;
        *(float4*)&Kd[jj][u0]     = *(const float4*)&kd[jj * U_ + u0];
        *(float4*)&Kd[jj][u0 + 4] = *(const float4*)&kd[jj * U_ + u0 + 4];
    }
    __syncthreads();

    const unsigned int psel = (q < 2) ? 0x05040100u : 0x07060302u;
    const unsigned char* fbase = ws + (size_t)a * 64 * 8192 + (size_t)lane * 16;
    union { unsigned int u[4]; bf16x8 v; } oc;
    oc.u[0] = 0x3F803F80u; oc.u[1] = 0x3F803F80u; oc.u[2] = 0x3F803F80u; oc.u[3] = 0x3F803F80u;
    const bf16x8 ONES = oc.v;
    const f32x4 vzero = (f32x4){0.f, 0.f, 0.f, 0.f};
    f32x4 S0 = vzero, S1 = vzero, S2 = vzero, S3 = vzero;
    bf16x8 KA[4], WA[4], KB[4], WB[4];

    auto LOADF = [&](bf16x8* K, bf16x8* W, int jj) {
        const unsigned char* p = fbase + (size_t)jj * 8192;
        #pragma unroll
        for (int i = 0; i < 4; ++i) {
            K[i] = *(const bf16x8*)(p + i * 1024);
            W[i] = *(const bf16x8*)(p + 4096 + i * 1024);
        }
    };
    auto BODY = [&](const bf16x8* K, const bf16x8* W, int j) {
        f32x4 ZA = vzero, ZB = vzero;
        ZA = __builtin_amdgcn_mfma_f32_16x16x32_bf16(Xh[0], K[0], ZA, 0, 0, 0);
        ZA = __builtin_amdgcn_mfma_f32_16x16x32_bf16(Xh[1], K[2], ZA, 0, 0, 0);
        ZB = __builtin_amdgcn_mfma_f32_16x16x32_bf16(Xh[0], K[1], ZB, 0, 0, 0);
        ZB = __builtin_amdgcn_mfma_f32_16x16x32_bf16(Xh[1], K[3], ZB, 0, 0, 0);
        const float kd0 = Kd[j][c], kd1 = Kd[j][16 + c];
        #pragma unroll
        for (int r = 0; r < 4; ++r) {
            const float xj = Xf[wv * 16 + q * 4 + r][j];
            const float e0 = __expf(ZA[r] - xj * kd0);
            const float e1 = __expf(ZB[r] - xj * kd1);
            Pbuf[wv][q * 4 + r][c] = pk_bf16(e0, e1);
        }
        asm volatile("s_waitcnt lgkmcnt(0)" ::: "memory");
        union { unsigned int u[4]; bf16x8 v; } E;
        {
            const uint4 pa = *(const uint4*)&Pbuf[wv][c][(q & 1) * 8];
            const uint4 pb = *(const uint4*)&Pbuf[wv][c][(q & 1) * 8 + 4];
            E.u[0] = __builtin_amdgcn_perm(pa.y, pa.x, psel);
            E.u[1] = __builtin_amdgcn_perm(pa.w, pa.z, psel);
            E.u[2] = __builtin_amdgcn_perm(pb.y, pb.x, psel);
            E.u[3] = __builtin_amdgcn_perm(pb.w, pb.z, psel);
        }
        const f32x4 sv = __builtin_amdgcn_mfma_f32_16x16x32_bf16(E.v, ONES, vzero, 0, 0, 0);
        f32x4 D0 = __builtin_amdgcn_mfma_f32_16x16x32_bf16(E.v, W[0], vzero, 0, 0, 0);
        f32x4 D1 = __builtin_amdgcn_mfma_f32_16x16x32_bf16(E.v, W[1], vzero, 0, 0, 0);
        f32x4 D2 = __builtin_amdgcn_mfma_f32_16x16x32_bf16(E.v, W[2], vzero, 0, 0, 0);
        f32x4 D3 = __builtin_amdgcn_mfma_f32_16x16x32_bf16(E.v, W[3], vzero, 0, 0, 0);
        #pragma unroll
        for (int r = 0; r < 4; ++r) {
            const float inv = __builtin_amdgcn_rcpf(sv[r]);
            S0[r] += D0[r] * inv;
            S1[r] += D1[r] * inv;
            S2[r] += D2[r] * inv;
            S3[r] += D3[r] * inv;
        }
    };

    LOADF(KA, WA, 0);
    for (int j = 0; j < 64; j += 2) {
        LOADF(KB, WB, j + 1);
        BODY(KA, WA, j);
        LOADF(KA, WA, (j + 2 < 64) ? (j + 2) : 63);
        BODY(KB, WB, j + 1);
    }
    const float sc = 1.f / 64.f;
    #pragma unroll
    for (int r = 0; r < 4; ++r) {
        const float e0 = __expf(S0[r] * sc);
        const float e1 = __expf(S1[r] * sc);
        const float e2 = __expf(S2[r] * sc);
        const float e3 = __expf(S3[r] * sc);
        float s = e0 + e1 + e2 + e3;
        s += __shfl_xor(s, 1);
        s += __shfl_xor(s, 2);
        s += __shfl_xor(s, 4);
        s += __shfl_xor(s, 8);
        const float inv = 1.f / s;
        const int bb = bt * 64 + wv * 16 + q * 4 + r;
        float* o = out + ((size_t)a * B_ + bb) * F_ + c;
        o[0]  = e0 * inv;
        o[16] = e1 * inv;
        o[32] = e2 * inv;
        o[48] = e3 * inv;
    }
}

extern "C" void kernel_launch(void* const* d_in, const int* in_sizes, int n_in,
                              void* d_out, int out_size, void* d_ws, size_t ws_size,
                              hipStream_t stream) {
    (void)in_sizes; (void)n_in; (void)out_size;
    const float* x    = (const float*)d_in[0];
    const float* kern = (const float*)d_in[1];
    float* out        = (float*)d_out;
    unsigned char* ws = (unsigned char*)d_ws;

    if (ws_size >= WS_NEED) {
        hipLaunchKernelGGL(ife_fused, dim3(512), dim3(256), 0, stream, x, kern, ws, out);
    } else {
        hipLaunchKernelGGL(ife_prep, dim3(F_ * A_), dim3(256), 0, stream, kern, ws);
        hipLaunchKernelGGL(ife_main, dim3(B_ / 64, A_), dim3(256), 0, stream, x, ws, out);
    }
}

// Round 7
// 122.345 us; speedup vs baseline: 2.8154x; 1.2307x over previous
//
#include <hip/hip_runtime.h>
#include <hip/hip_bf16.h>
#include <math.h>

#define B_ 4096
#define F_ 64
#define A_ 8
#define U_ 32

typedef float f32x4 __attribute__((ext_vector_type(4)));
typedef short bf16x8 __attribute__((ext_vector_type(8)));

static __device__ __forceinline__ unsigned int pk_bf16(float lo, float hi) {
    union { __hip_bfloat162 h2; unsigned int u; } cv;
    cv.h2 = __float22bfloat162_rn(make_float2(lo, hi));
    return cv.u;
}
static __device__ __forceinline__ float rb(float f) {   // fp32 -> bf16 -> fp32 (RNE)
    unsigned int u = __float_as_uint(f);
    u += 0x7FFFu + ((u >> 16) & 1u);
    return __uint_as_float(u & 0xFFFF0000u);
}

// Single kernel, ZERO workspace, ZERO grid barriers.
// Block = (a, 64-row batch tile); full j=0..63 loop; per-j in-block frag prep:
//   thread t builds the 16B slot (frag id = wave, lane slot = t&63) of both the
//   K B-frag and W B-frag in a double-buffered LDS frag store (layout identical
//   to the proven r3/r6 prep), one __syncthreads per j.
__global__ __launch_bounds__(256, 2)
void ife_onepass(const float* __restrict__ x,     // [B, F]
                 const float* __restrict__ kern,  // [j=F, A, F, U]
                 float* __restrict__ out)         // [A, B, F]
{
    const int a = blockIdx.y, bt = blockIdx.x, t = threadIdx.x;
    const int wv = t >> 6, lane = t & 63, q = lane >> 4, c = lane & 15;

    __shared__ float Xf[64][66];                            // rb-rounded X tile
    __shared__ __align__(16) unsigned int Pbuf[4][16][20];  // wave-private E round-trip
    __shared__ __align__(16) uint4 Kfr[2][4][64];           // dbuf K B-frags [buf][frag][lane]
    __shared__ __align__(16) uint4 Wfr[2][4][64];           // dbuf W B-frags [buf][frag][lane]

    // ---- X A-frags (m=c, k=kc*32+q*8+jj), pure bf16 ----
    bf16x8 Xh[2];
    {
        const float* xr = x + (size_t)(bt * 64 + wv * 16 + c) * F_;
        #pragma unroll
        for (int kc = 0; kc < 2; ++kc) {
            const float4 va = *(const float4*)&xr[kc * 32 + q * 8];
            const float4 vb = *(const float4*)&xr[kc * 32 + q * 8 + 4];
            union { unsigned int u[4]; bf16x8 v; } H;
            H.u[0] = pk_bf16(va.x, va.y);
            H.u[1] = pk_bf16(va.z, va.w);
            H.u[2] = pk_bf16(vb.x, vb.y);
            H.u[3] = pk_bf16(vb.z, vb.w);
            Xh[kc] = H.v;
        }
    }
    // ---- Xf: rb-rounded fp32 X tile (broadcast reads for mask correction) ----
    {
        const int row = t >> 2, cb = (t & 3) * 16;
        const float* xsrc = x + (size_t)(bt * 64 + row) * F_ + cb;
        #pragma unroll
        for (int i = 0; i < 16; i += 4) {
            const float4 v = *(const float4*)&xsrc[i];
            Xf[row][cb + i]     = rb(v.x);
            Xf[row][cb + i + 1] = rb(v.y);
            Xf[row][cb + i + 2] = rb(v.z);
            Xf[row][cb + i + 3] = rb(v.w);
        }
    }

    // prep roles for this thread: it owns frag id = wv, lane slot = lane.
    const int kcP = wv >> 1, utP = wv & 1;   // K-frag (kc,ut) = frag id kc*2+ut = wv
    // W-frag id ft = wv: source row f = wv*16 + c, u = q*8..q*8+7

    float4 w0, w1; float kr[8]; float2 kdn;
    auto PREP_LOAD = [&](int jn) {
        const float* kj = kern + ((size_t)jn * A_ + a) * (F_ * U_);
        const float* wrow = kj + (wv * 16 + c) * U_ + q * 8;     // coalesced 2KB/wave
        w0 = *(const float4*)wrow;
        w1 = *(const float4*)(wrow + 4);
        const float* kcol = kj + (kcP * 32 + q * 8) * U_ + utP * 16 + c;
        #pragma unroll
        for (int i = 0; i < 8; ++i) kr[i] = kcol[i * U_];        // 8 rows, 4-line coalesced
        kdn.x = kj[jn * U_ + c];                                 // K[jn][a][jn][u] (broadcast)
        kdn.y = kj[jn * U_ + 16 + c];
    };
    auto PREP_STORE = [&](int pb) {
        uint4 kw, ww;
        kw.x = pk_bf16(kr[0], kr[1]);
        kw.y = pk_bf16(kr[2], kr[3]);
        kw.z = pk_bf16(kr[4], kr[5]);
        kw.w = pk_bf16(kr[6], kr[7]);
        ww.x = pk_bf16(__expf(2.f * w0.x), __expf(2.f * w0.y));
        ww.y = pk_bf16(__expf(2.f * w0.z), __expf(2.f * w0.w));
        ww.z = pk_bf16(__expf(2.f * w1.x), __expf(2.f * w1.y));
        ww.w = pk_bf16(__expf(2.f * w1.z), __expf(2.f * w1.w));
        Kfr[pb][wv][lane] = kw;
        Wfr[pb][wv][lane] = ww;
    };

    // ---- prologue: prep j=0 into buf 0 ----
    PREP_LOAD(0);
    PREP_STORE(0);
    float2 kdc = kdn;
    __syncthreads();   // covers Xf/X stores + frag buf 0

    const unsigned int psel = (q < 2) ? 0x05040100u : 0x07060302u;
    union { unsigned int u[4]; bf16x8 v; } oc;
    oc.u[0] = 0x3F803F80u; oc.u[1] = 0x3F803F80u; oc.u[2] = 0x3F803F80u; oc.u[3] = 0x3F803F80u;
    const bf16x8 ONES = oc.v;
    const f32x4 vzero = (f32x4){0.f, 0.f, 0.f, 0.f};
    f32x4 S0 = vzero, S1 = vzero, S2 = vzero, S3 = vzero;

    for (int j = 0; j < 64; ++j) {
        const int buf = j & 1;
        // 1. issue global loads for j+1 (clamped refetch at the end, harmless)
        PREP_LOAD((j + 1 < 64) ? (j + 1) : 63);

        // 2. read current frags (lane-linear b128, conflict-free)
        union { uint4 u; bf16x8 v; } K[4], W[4];
        #pragma unroll
        for (int i = 0; i < 4; ++i) {
            K[i].u = Kfr[buf][i][lane];
            W[i].u = Wfr[buf][i][lane];
        }

        // 3. body: Z = X @ K
        f32x4 ZA = vzero, ZB = vzero;
        ZA = __builtin_amdgcn_mfma_f32_16x16x32_bf16(Xh[0], K[0].v, ZA, 0, 0, 0);
        ZA = __builtin_amdgcn_mfma_f32_16x16x32_bf16(Xh[1], K[2].v, ZA, 0, 0, 0);
        ZB = __builtin_amdgcn_mfma_f32_16x16x32_bf16(Xh[0], K[1].v, ZB, 0, 0, 0);
        ZB = __builtin_amdgcn_mfma_f32_16x16x32_bf16(Xh[1], K[3].v, ZB, 0, 0, 0);

        // rank-1 mask correction + exp (unnormalized), wave-private LDS round-trip
        const float kd0 = rb(kdc.x), kd1 = rb(kdc.y);
        #pragma unroll
        for (int r = 0; r < 4; ++r) {
            const float xj = Xf[wv * 16 + q * 4 + r][j];
            const float e0 = __expf(ZA[r] - xj * kd0);
            const float e1 = __expf(ZB[r] - xj * kd1);
            Pbuf[wv][q * 4 + r][c] = pk_bf16(e0, e1);
        }
        asm volatile("s_waitcnt lgkmcnt(0)" ::: "memory");
        union { unsigned int u[4]; bf16x8 v; } E;
        {
            const uint4 pa = *(const uint4*)&Pbuf[wv][c][(q & 1) * 8];
            const uint4 pb = *(const uint4*)&Pbuf[wv][c][(q & 1) * 8 + 4];
            E.u[0] = __builtin_amdgcn_perm(pa.y, pa.x, psel);
            E.u[1] = __builtin_amdgcn_perm(pa.w, pa.z, psel);
            E.u[2] = __builtin_amdgcn_perm(pb.y, pb.x, psel);
            E.u[3] = __builtin_amdgcn_perm(pb.w, pb.z, psel);
        }

        // row sums via ones-MFMA; normalize while accumulating
        const f32x4 sv = __builtin_amdgcn_mfma_f32_16x16x32_bf16(E.v, ONES, vzero, 0, 0, 0);
        f32x4 D0 = __builtin_amdgcn_mfma_f32_16x16x32_bf16(E.v, W[0].v, vzero, 0, 0, 0);
        f32x4 D1 = __builtin_amdgcn_mfma_f32_16x16x32_bf16(E.v, W[1].v, vzero, 0, 0, 0);
        f32x4 D2 = __builtin_amdgcn_mfma_f32_16x16x32_bf16(E.v, W[2].v, vzero, 0, 0, 0);
        f32x4 D3 = __builtin_amdgcn_mfma_f32_16x16x32_bf16(E.v, W[3].v, vzero, 0, 0, 0);
        #pragma unroll
        for (int r = 0; r < 4; ++r) {
            const float inv = __builtin_amdgcn_rcpf(sv[r]);
            S0[r] += D0[r] * inv;
            S1[r] += D1[r] * inv;
            S2[r] += D2[r] * inv;
            S3[r] += D3[r] * inv;
        }

        // 4+5. convert j+1 raws and store into the other buffer
        PREP_STORE(buf ^ 1);
        // 6. one barrier per j: frag writes visible before next iter's reads;
        //    WAR on buf^1 protected by the previous iteration's barrier.
        __syncthreads();
        kdc = kdn;
    }

    // ---- epilogue: mean over j, softmax over f (flat scores), coalesced store ----
    const float sc = 1.f / 64.f;
    #pragma unroll
    for (int r = 0; r < 4; ++r) {
        const float e0 = __expf(S0[r] * sc);
        const float e1 = __expf(S1[r] * sc);
        const float e2 = __expf(S2[r] * sc);
        const float e3 = __expf(S3[r] * sc);
        float s = e0 + e1 + e2 + e3;
        s += __shfl_xor(s, 1);
        s += __shfl_xor(s, 2);
        s += __shfl_xor(s, 4);
        s += __shfl_xor(s, 8);
        const float inv = 1.f / s;
        const int bb = bt * 64 + wv * 16 + q * 4 + r;
        float* o = out + ((size_t)a * B_ + bb) * F_ + c;
        o[0]  = e0 * inv;
        o[16] = e1 * inv;
        o[32] = e2 * inv;
        o[48] = e3 * inv;
    }
}

extern "C" void kernel_launch(void* const* d_in, const int* in_sizes, int n_in,
                              void* d_out, int out_size, void* d_ws, size_t ws_size,
                              hipStream_t stream) {
    (void)in_sizes; (void)n_in; (void)out_size; (void)d_ws; (void)ws_size;
    const float* x    = (const float*)d_in[0];   // [B, F]
    const float* kern = (const float*)d_in[1];   // [F, A, F, U]
    float* out        = (float*)d_out;           // [A, B, F]

    // workspace deliberately untouched (testing the ws-poison-gap theory)
    hipLaunchKernelGGL(ife_onepass, dim3(B_ / 64, A_), dim3(256), 0, stream, x, kern, out);
}